// Round 1
// 314.783 us; speedup vs baseline: 1.0459x; 1.0459x over previous
//
#include <hip/hip_runtime.h>
#include <stdint.h>

#define DD 512
#define MTOT 32768  // B*N = 8*4096

typedef float f32x4 __attribute__((ext_vector_type(4)));
typedef __bf16 bf16x8 __attribute__((ext_vector_type(8)));

static __device__ __forceinline__ unsigned short f2bf(float f) {
  union { float f; unsigned int u; } c; c.f = f;
  unsigned int r = c.u + 0x7fffu + ((c.u >> 16) & 1u);
  return (unsigned short)(r >> 16);
}
static __device__ __forceinline__ float bf2f(unsigned short h) {
  union { unsigned int u; float f; } c; c.u = ((unsigned int)h) << 16;
  return c.f;
}

union FragU { uint4 u; bf16x8 b; };

static __device__ __forceinline__ void load_lds16(const void* g, void* l) {
  __builtin_amdgcn_global_load_lds(
      (const __attribute__((address_space(1))) void*)g,
      (__attribute__((address_space(3))) void*)l, 16, 0, 0);
}

// ---- three 512x512 weights -> bf16, plus zeroing of the stats buffers ----
// blocks [0,768): weight cvt. blocks [768,864): zero stats (3*MTOT floats).
__global__ __launch_bounds__(256) void cvt3w_k(const float* __restrict__ W0,
    const float* __restrict__ W1, const float* __restrict__ W2,
    unsigned short* __restrict__ D0, unsigned short* __restrict__ D1,
    unsigned short* __restrict__ D2, float* __restrict__ stats) {
  int slab = blockIdx.x >> 8;
  if (slab == 3) {
    int i = ((blockIdx.x - 768) * 256 + threadIdx.x) * 4;  // [0, 3*MTOT)
    *(float4*)(stats + i) = make_float4(0.f, 0.f, 0.f, 0.f);
    return;
  }
  int off = ((blockIdx.x & 255) * 256 + threadIdx.x) * 4;
  const float* s = slab == 0 ? W0 : slab == 1 ? W1 : W2;
  unsigned short* d = slab == 0 ? D0 : slab == 1 ? D1 : D2;
  float4 f = *(const float4*)(s + off);
  ushort4 h;
  h.x = f2bf(f.x); h.y = f2bf(f.y); h.z = f2bf(f.z); h.w = f2bf(f.w);
  *(ushort4*)(d + off) = h;
}

// ---------------- W'p[b] = Wp * G[b,:] (broadcast over rows) --------------
__global__ __launch_bounds__(256) void scalew_k(const float* __restrict__ Wp,
    const float* __restrict__ G, unsigned short* __restrict__ out) {
  int i = (blockIdx.x * 256 + threadIdx.x) * 4;  // [0, 8*262144)
  int b = i >> 18;
  int rem = i & 262143;
  int d = rem & 511;
  float4 w = *(const float4*)(Wp + rem);
  float4 g = *(const float4*)(G + b * DD + d);
  ushort4 h;
  h.x = f2bf(w.x * g.x); h.y = f2bf(w.y * g.y);
  h.z = f2bf(w.z * g.z); h.w = f2bf(w.w * g.w);
  *(ushort4*)(out + i) = h;
}

// ---------------- GEMM: C[m,n] = sum_k X[m,k] * W[n,k] (+epilogue) --------
// m97 structure: 128x128 tile, BK=64, XOR-swizzled LDS (kseg ^ (row&7)).
// XFP32: A operand is fp32 in global; reg-stage (load f32x4 x2 -> f2bf ->
//        swizzled ds_write_b128), B stays on the global_load_lds fast path.
// BBATCH: W indexed per batch (row0>>12).
// EMODE: 1 = +bias -> bf16, row ssq + wg-dot atomics (Q GEMM)
//        2 = +bias -> bf16, row ssq atomics            (K GEMM)
//        3 = kinv*acc + bias + qinv*Qadd -> bf16       (P GEMM)
//        4 = +bias -> fp32                              (final GEMM)
template<int XFP32, int BBATCH, int EMODE>
__global__ __launch_bounds__(256) void gemm_k(
    const void* __restrict__ Xv,
    const unsigned short* __restrict__ Wb,
    const float* __restrict__ bias,
    const unsigned short* __restrict__ Qadd,
    const float* __restrict__ wg,
    float* __restrict__ ssq,
    float* __restrict__ Pdot,
    const float* __restrict__ qinv,
    const float* __restrict__ kinv,
    void* __restrict__ Cv) {
  __shared__ unsigned short As[128 * 64];
  __shared__ unsigned short Bs[128 * 64];
  const int tid = threadIdx.x;
  const int lane = tid & 63, wave = tid >> 6;
  const int row0 = blockIdx.x * 128, col0 = blockIdx.y * 128;
  const unsigned short* W = Wb + (BBATCH ? (size_t)(row0 >> 12) * 262144 : 0);

  const int sr = lane >> 3;    // row within 8-row slab, == row&7
  const int c8 = lane & 7;     // kseg index
  // bf16 path: source column pre-swizzled, LDS write is linear (lane*16B)
  const unsigned short* Ag =
      (const unsigned short*)Xv + (size_t)(row0 + wave * 32 + sr) * DD + (c8 ^ sr) * 8;
  const unsigned short* Bg = W + (size_t)(col0 + wave * 32 + sr) * DD + (c8 ^ sr) * 8;
  // fp32 path: source linear, LDS write column swizzled
  const float* Agf = (const float*)Xv + (size_t)(row0 + wave * 32 + sr) * DD + c8 * 8;
  const int ldsb = wave * 32 * 64;  // elem offset of this wave's 32-row slab
  const int awr = ldsb + sr * 64 + (c8 ^ sr) * 8;  // swizzled write slot (fp32 path)

  const int fr = lane & 15, quad = lane >> 4;
  const int wr = (wave >> 1) * 64, wc = (wave & 1) * 64;
  const int sw0 = ((quad ^ (fr & 7)) * 8);
  const int sw1 = (((quad + 4) ^ (fr & 7)) * 8);

  f32x4 acc[4][4] = {};

  for (int k0 = 0; k0 < DD; k0 += 64) {
#pragma unroll
    for (int q = 0; q < 4; q++) {
      if (XFP32) {
        const float* s = Agf + (size_t)q * 8 * DD + k0;
        f32x4 f0 = *(const f32x4*)s;
        f32x4 f1 = *(const f32x4*)(s + 4);
        union { uint4 u; unsigned short h[8]; } pk;
        pk.h[0] = f2bf(f0.x); pk.h[1] = f2bf(f0.y);
        pk.h[2] = f2bf(f0.z); pk.h[3] = f2bf(f0.w);
        pk.h[4] = f2bf(f1.x); pk.h[5] = f2bf(f1.y);
        pk.h[6] = f2bf(f1.z); pk.h[7] = f2bf(f1.w);
        *(uint4*)&As[awr + q * 8 * 64] = pk.u;
      } else {
        load_lds16(Ag + (size_t)q * 8 * DD + k0, As + ldsb + q * 8 * 64);
      }
      load_lds16(Bg + (size_t)q * 8 * DD + k0, Bs + ldsb + q * 8 * 64);
    }
    __syncthreads();
#pragma unroll
    for (int kk = 0; kk < 2; kk++) {
      const int sw = kk ? sw1 : sw0;
      bf16x8 af[4], bfr[4];
#pragma unroll
      for (int i = 0; i < 4; i++) {
        FragU u; u.u = *(const uint4*)&As[(wr + i * 16 + fr) * 64 + sw];
        af[i] = u.b;
      }
#pragma unroll
      for (int j = 0; j < 4; j++) {
        FragU u; u.u = *(const uint4*)&Bs[(wc + j * 16 + fr) * 64 + sw];
        bfr[j] = u.b;
      }
#pragma unroll
      for (int i = 0; i < 4; i++)
#pragma unroll
        for (int j = 0; j < 4; j++)
          acc[i][j] = __builtin_amdgcn_mfma_f32_16x16x32_bf16(af[i], bfr[j], acc[i][j], 0, 0, 0);
    }
    __syncthreads();
  }

  // epilogue: C/D layout col=lane&15, row=(lane>>4)*4+reg
  const int colbase = col0 + wc + fr;
  float bv4[4];
#pragma unroll
  for (int j = 0; j < 4; j++) bv4[j] = bias[colbase + j * 16];
  float wg4[4];
  if (EMODE == 1) {
#pragma unroll
    for (int j = 0; j < 4; j++) wg4[j] = wg[colbase + j * 16];
  }
#pragma unroll
  for (int i = 0; i < 4; i++) {
#pragma unroll
    for (int r = 0; r < 4; r++) {
      const int row = row0 + wr + i * 16 + quad * 4 + r;
      float ki = 1.f, qi = 1.f;
      if (EMODE == 3) { ki = kinv[row]; qi = qinv[row]; }
      float ssum = 0.f, dsum = 0.f;
#pragma unroll
      for (int j = 0; j < 4; j++) {
        size_t idx = (size_t)row * DD + colbase + j * 16;
        float v;
        if (EMODE == 3) v = acc[i][j][r] * ki + bv4[j] + qi * bf2f(Qadd[idx]);
        else            v = acc[i][j][r] + bv4[j];
        if (EMODE != 4) ((unsigned short*)Cv)[idx] = f2bf(v);
        else            ((float*)Cv)[idx] = v;
        if (EMODE == 1 || EMODE == 2) ssum += v * v;
        if (EMODE == 1) dsum += v * wg4[j];
      }
      if (EMODE == 1 || EMODE == 2) {
#pragma unroll
        for (int m = 1; m < 16; m <<= 1) ssum += __shfl_xor(ssum, m, 64);
        if (EMODE == 1) {
#pragma unroll
          for (int m = 1; m < 16; m <<= 1) dsum += __shfl_xor(dsum, m, 64);
        }
        if (fr == 0) {
          atomicAdd(&ssq[row], ssum);
          if (EMODE == 1) atomicAdd(&Pdot[row], dsum);
        }
      }
    }
  }
}

// ---- per-row inv norms, pooling weights, per-batch 1/||A||, zero G -------
__global__ __launch_bounds__(512) void finstat_k(const float* __restrict__ ssqQ,
    const float* __restrict__ ssqK, const float* __restrict__ P,
    float* __restrict__ qinv, float* __restrict__ kinv,
    float* __restrict__ Araw2, float* __restrict__ sinv, float* __restrict__ G) {
  const int b = blockIdx.x, t = threadIdx.x;
  G[b * DD + t] = 0.f;
  float ss = 0.f;
  for (int i = t; i < 4096; i += 512) {
    int n = b * 4096 + i;
    float qi = 1.0f / fmaxf(sqrtf(ssqQ[n]), 1e-12f);
    float ki = 1.0f / fmaxf(sqrtf(ssqK[n]), 1e-12f);
    qinv[n] = qi; kinv[n] = ki;
    float A = P[n] * qi;          // dot of normalized Q row with wg
    Araw2[n] = A * qi;            // pooling weight (pre sinv): A * qinv
    ss += A * A;
  }
#pragma unroll
  for (int m = 1; m < 64; m <<= 1) ss += __shfl_xor(ss, m, 64);
  __shared__ float sred[8];
  if ((t & 63) == 0) sred[t >> 6] = ss;
  __syncthreads();
  if (t == 0) {
    float tot = 0.f;
    for (int i = 0; i < 8; i++) tot += sred[i];
    sinv[b] = 1.0f / fmaxf(sqrtf(tot), 1e-12f);
  }
}

// ------- G[b,d] = sum_n (Araw2[b,n]*sinv[b]) * Qraw[b,n,d] ---------------
__global__ __launch_bounds__(256) void pool_k(const float* __restrict__ Araw2,
    const float* __restrict__ sinv, const unsigned short* __restrict__ Q,
    float* __restrict__ G) {
  const int b = blockIdx.x >> 5;
  const int chunk = blockIdx.x & 31;
  const int rbase = b * 4096 + chunk * 128;
  const float si = sinv[b];
  const int t = threadIdx.x;
  float a0 = 0.f, a1 = 0.f;
  for (int r = 0; r < 128; r++) {
    float w = Araw2[rbase + r] * si;
    const unsigned short* qr = Q + (size_t)(rbase + r) * DD;
    a0 += w * bf2f(qr[t]);
    a1 += w * bf2f(qr[t + 256]);
  }
  atomicAdd(&G[b * DD + t], a0);
  atomicAdd(&G[b * DD + t + 256], a1);
}

extern "C" void kernel_launch(void* const* d_in, const int* in_sizes, int n_in,
                              void* d_out, int out_size, void* d_ws, size_t ws_size,
                              hipStream_t stream) {
  const float* a   = (const float*)d_in[0];
  const float* b   = (const float*)d_in[1];
  const float* Wq  = (const float*)d_in[2];
  const float* bq  = (const float*)d_in[3];
  const float* Wk  = (const float*)d_in[4];
  const float* bk  = (const float*)d_in[5];
  const float* wg  = (const float*)d_in[6];
  const float* Wp  = (const float*)d_in[7];
  const float* bp  = (const float*)d_in[8];
  const float* Wf  = (const float*)d_in[9];
  const float* bfb = (const float*)d_in[10];

  const size_t WELEM = 262144;          // 512*512
  const size_t MD = (size_t)MTOT * DD;  // 16,777,216 elems

  unsigned short* O1b = (unsigned short*)d_ws;  // O1 intermediate
  unsigned short* Qb  = O1b + MD;               // raw Q (bf16)
  unsigned short* Kb  = Qb + MD;                // raw K (bf16)
  unsigned short* Wqb = Kb + MD;
  unsigned short* Wkb = Wqb + WELEM;
  unsigned short* Wfb = Wkb + WELEM;
  unsigned short* Wps = Wfb + WELEM;            // 8 * 262144 per-batch scaled Wp
  float* stats = (float*)(Wps + 8 * WELEM);
  float* ssqQ  = stats;                 // [MTOT]  zeroed by cvt3w_k
  float* ssqK  = stats + MTOT;          // [MTOT]  zeroed by cvt3w_k
  float* Pd    = stats + 2 * MTOT;      // [MTOT]  zeroed by cvt3w_k
  float* qinv  = stats + 3 * MTOT;
  float* kinv  = stats + 4 * MTOT;
  float* Araw2 = stats + 5 * MTOT;
  float* sinv  = stats + 6 * MTOT;      // [8]
  float* G     = sinv + 64;             // [8*512]

  // weights -> bf16, zero stat accumulators
  cvt3w_k<<<dim3(864), dim3(256), 0, stream>>>(Wq, Wk, Wf, Wqb, Wkb, Wfb, stats);
  // Qraw = a*Wq^T + bq (fp32 A fused-convert); row ssq + wg dot
  gemm_k<1, 0, 1><<<dim3(256, 4), dim3(256), 0, stream>>>(
      a, Wqb, bq, nullptr, wg, ssqQ, Pd, nullptr, nullptr, Qb);
  // Kraw = b*Wk^T + bk; row ssq
  gemm_k<1, 0, 2><<<dim3(256, 4), dim3(256), 0, stream>>>(
      b, Wkb, bk, nullptr, nullptr, ssqK, nullptr, nullptr, nullptr, Kb);
  // per-row inv norms + pooling weights + per-batch sinv + zero G
  finstat_k<<<dim3(8), dim3(512), 0, stream>>>(ssqQ, ssqK, Pd, qinv, kinv, Araw2, sinv, G);
  // G[b,d] learned pooling over raw Q
  pool_k<<<dim3(256), dim3(256), 0, stream>>>(Araw2, sinv, Qb, G);
  // fold G into Wp per batch
  scalew_k<<<dim3(2048), dim3(256), 0, stream>>>(Wp, G, Wps);
  // O1 = kinv*(Kraw*(Wp.G)^T) + bp + qinv*Qraw
  gemm_k<0, 1, 3><<<dim3(256, 4), dim3(256), 0, stream>>>(
      Kb, Wps, bp, Qb, nullptr, nullptr, nullptr, qinv, kinv, O1b);
  // out = O1*Wf^T + bf (fp32)
  gemm_k<0, 0, 4><<<dim3(256, 4), dim3(256), 0, stream>>>(
      O1b, Wfb, bfb, nullptr, nullptr, nullptr, nullptr, nullptr, nullptr, d_out);
}